// Round 1
// baseline (210.334 us; speedup 1.0000x reference)
//
#include <hip/hip_runtime.h>
#include <stdint.h>

// SimCLR loss, B=4096, D=512, TAU=0.1.  out[0]=loss, out[1]=acc(%).
//
// Round 11: merged a/b passes + counted-vmcnt pipeline + full-width swizzle.
//  - Both views' row fragments resident (ar/br, 128 VGPR): each staged column
//    tile feeds BOTH full_a and full_b MFMAs -> staging traffic halved, LDS
//    bytes per MFMA halved (16 ds_read_b128 : 16 MFMA per iter).
//  - 32-col tiles (16 KB) x 4 LDS buffers, 3-deep prefetch, counted
//    s_waitcnt vmcnt(8) + raw s_barrier per iter (T3/T4): loads span 3
//    barriers, never drained to 0 in steady state.
//  - 5-bit XOR swizzle (physical chunk p of col c holds logical p^c):
//    ds_read_b128 granule (4i+h)^n5 is a bijection per 32-lane half ->
//    2 lanes/granule (free) vs previous 3-bit swizzle's 4-way conflict.
//  - s_setprio(1) around the MFMA cluster (T5).

#define BN 4096
#define DK 512            // K elements = bytes per row in fp8
#define NSPLIT 16
#define NT 16             // 32-col tiles per split
#define NEG_BIG -1e30f
#define SCL 0.15625f      // 1/(8*8*TAU)
#define SCL2 0.225396744f // SCL * log2(e)
#define C2 14.4269504f    // 10 * log2(e)
#define TILE_BYTES (32 * DK)  // 16 KB per 32-col fp8 tile

typedef __attribute__((ext_vector_type(16))) float floatx16;
typedef __attribute__((ext_vector_type(8))) int intx8;

// ---------------- prep: normalize, fp8-pack (K-permuted), label, zero -----
// Permuted layout: byte position kc2*32 + h*16 + t*8 + j holds original
// k = kc2*32 + t*16 + h*8 + j.  16B chunk (kc2,h) = K=16-sub-block operand
// bytes; two consecutive chunks (2i,h),(2i+1,h) = one K=64 MX operand half.
__global__ void __launch_bounds__(256) prep_kernel(
    const float* __restrict__ A, const float* __restrict__ Bv,
    unsigned char* __restrict__ An, unsigned char* __restrict__ Bn,
    float* __restrict__ diag, float* __restrict__ out) {
  if (blockIdx.x == 0 && threadIdx.x < 2) out[threadIdx.x] = 0.0f;
  const int w = threadIdx.x >> 6, lane = threadIdx.x & 63;
  const int row = blockIdx.x * 4 + w;
  const float4* pa4 = (const float4*)(A + (size_t)row * DK);
  const float4* pb4 = (const float4*)(Bv + (size_t)row * DK);
  float4 a0 = pa4[lane * 2], a1 = pa4[lane * 2 + 1];  // k = lane*8 .. +7
  float4 b0 = pb4[lane * 2], b1 = pb4[lane * 2 + 1];
  float ssa = a0.x * a0.x + a0.y * a0.y + a0.z * a0.z + a0.w * a0.w +
              a1.x * a1.x + a1.y * a1.y + a1.z * a1.z + a1.w * a1.w;
  float ssb = b0.x * b0.x + b0.y * b0.y + b0.z * b0.z + b0.w * b0.w +
              b1.x * b1.x + b1.y * b1.y + b1.z * b1.z + b1.w * b1.w;
  float sab = a0.x * b0.x + a0.y * b0.y + a0.z * b0.z + a0.w * b0.w +
              a1.x * b1.x + a1.y * b1.y + a1.z * b1.z + a1.w * b1.w;
#pragma unroll
  for (int off = 32; off > 0; off >>= 1) {
    ssa += __shfl_xor(ssa, off);
    ssb += __shfl_xor(ssb, off);
    sab += __shfl_xor(sab, off);
  }
  float na = fmaxf(sqrtf(ssa), 1e-12f);
  float nb = fmaxf(sqrtf(ssb), 1e-12f);
  const float s = 8.0f;  // fp8 pre-scale: keeps elems mid-range in e4m3
  float sa = s / na, sb = s / nb;
  const int doff = (lane >> 2) * 32 + (lane & 1) * 16 + ((lane >> 1) & 1) * 8;
  {
    int v0 = __builtin_amdgcn_cvt_pk_fp8_f32(a0.x * sa, a0.y * sa, 0, false);
    v0 = __builtin_amdgcn_cvt_pk_fp8_f32(a0.z * sa, a0.w * sa, v0, true);
    int v1 = __builtin_amdgcn_cvt_pk_fp8_f32(a1.x * sa, a1.y * sa, 0, false);
    v1 = __builtin_amdgcn_cvt_pk_fp8_f32(a1.z * sa, a1.w * sa, v1, true);
    int2 pv; pv.x = v0; pv.y = v1;
    *(int2*)(An + (size_t)row * DK + doff) = pv;
  }
  {
    int v0 = __builtin_amdgcn_cvt_pk_fp8_f32(b0.x * sb, b0.y * sb, 0, false);
    v0 = __builtin_amdgcn_cvt_pk_fp8_f32(b0.z * sb, b0.w * sb, v0, true);
    int v1 = __builtin_amdgcn_cvt_pk_fp8_f32(b1.x * sb, b1.y * sb, 0, false);
    v1 = __builtin_amdgcn_cvt_pk_fp8_f32(b1.z * sb, b1.w * sb, v1, true);
    int2 pv; pv.x = v0; pv.y = v1;
    *(int2*)(Bn + (size_t)row * DK + doff) = pv;
  }
  if (lane == 0) diag[row] = (sab / (na * nb)) * 10.0f;  // exact fp32 /TAU
}

// ---------------- tiles: MX fp8 MFMA, merged a/b, pipelined staging -------
// grid = (32 row-blocks, 16 col-splits) = 512 blocks = 2/CU. 4 waves/block,
// wave owns 32 rows of BOTH views. Each split covers 512 cols of ONE view
// (splits 0-7: An cols, 8-15: Bn cols); per staged tile compute a-rows@tile
// (-> full_a) and b-rows@tile (-> full_b).
__global__ void __launch_bounds__(256, 2) tiles_kernel(
    const unsigned char* __restrict__ An, const unsigned char* __restrict__ Bn,
    float* __restrict__ pSA, float* __restrict__ pMA, float* __restrict__ pSB) {
  __shared__ __align__(16) unsigned char smem[4 * TILE_BYTES];  // 64 KB

  const int rb = blockIdx.x;     // 0..31 (128-row panel)
  const int split = blockIdx.y;  // 0..15
  const int tid = threadIdx.x;
  const int lane = tid & 63, w = tid >> 6;
  const int n5 = lane & 31, h = lane >> 5;
  const int r0 = rb * 128;
  const int myrow = r0 + w * 32 + n5;
  const int csplit = split & 7;
  const unsigned char* __restrict__ csrc = (split < 8) ? An : Bn;

  // K=64 MX row operands for BOTH views: xr[i] = chunks (2i,h)||(2i+1,h)
  intx8 ar[8], br[8];
  {
    const unsigned char* pa = An + (size_t)myrow * DK + h * 16;
    const unsigned char* pb = Bn + (size_t)myrow * DK + h * 16;
#pragma unroll
    for (int i = 0; i < 8; ++i) {
      int4 c0 = *(const int4*)(pa + i * 64);
      int4 c1 = *(const int4*)(pa + i * 64 + 32);
      intx8 va = {c0.x, c0.y, c0.z, c0.w, c1.x, c1.y, c1.z, c1.w};
      ar[i] = va;
      int4 d0 = *(const int4*)(pb + i * 64);
      int4 d1 = *(const int4*)(pb + i * 64 + 32);
      intx8 vb = {d0.x, d0.y, d0.z, d0.w, d1.x, d1.y, d1.z, d1.w};
      br[i] = vb;
    }
  }

  float la[16], lb[16], mx[16];
#pragma unroll
  for (int r = 0; r < 16; ++r) { la[r] = 0.f; lb[r] = 0.f; mx[r] = NEG_BIG; }

  // stage one 32-col tile (16 KB): wave w stages colpairs w*4..w*4+3.
  // DMA dest is linear (base + laneid*16): lane (h,n5) -> col cp*2+h, phys
  // chunk n5.  5-bit XOR swizzle via pre-swizzled global source: physical
  // chunk p of col cl holds logical chunk p^cl.
  auto stage = [&](int bu, int t) {
    unsigned char* buf = smem + bu * TILE_BYTES;
    const int cb = csplit * 512 + t * 32;
#pragma unroll
    for (int ii = 0; ii < 4; ++ii) {
      const int cp = w * 4 + ii;
      const int cl = cp * 2 + h;
      const unsigned char* src =
          csrc + (size_t)(cb + cl) * DK + ((n5 ^ cl) * 16);
      __builtin_amdgcn_global_load_lds(
          (const __attribute__((address_space(1))) void*)src,
          (__attribute__((address_space(3))) void*)(buf + cp * 1024),
          16, 0, 0);
    }
  };

  // prime the pipeline 3 deep (frag loads above are older in vmcnt order,
  // so vmcnt(8) at u=0 drains them too -- one-time cost, still correct)
  stage(0, 0);
  stage(1, 1);
  stage(2, 2);

  const unsigned char* bb = smem + (size_t)n5 * DK;

#pragma unroll
  for (int u = 0; u < NT; ++u) {
    // tile u's 4 loads are complete once <=8 newer ops remain (t_{u+1},t_{u+2})
    if (u <= NT - 3)      asm volatile("s_waitcnt vmcnt(8)" ::: "memory");
    else if (u == NT - 2) asm volatile("s_waitcnt vmcnt(4)" ::: "memory");
    else                  asm volatile("s_waitcnt vmcnt(0)" ::: "memory");
    __builtin_amdgcn_s_barrier();
    __builtin_amdgcn_sched_barrier(0);
    // after the barrier everyone has finished reading tile u-1, so its
    // buffer ((u+3)&3) may be overwritten now
    if (u + 3 < NT) stage((u + 3) & 3, u + 3);

    floatx16 ya, yb;
#pragma unroll
    for (int r = 0; r < 16; ++r) { ya[r] = 0.f; yb[r] = 0.f; }

    const unsigned char* bt = bb + (u & 3) * TILE_BYTES;
    __builtin_amdgcn_s_setprio(1);
#pragma unroll
    for (int i = 0; i < 8; ++i) {
      // col n5's K=64 operand: logical chunks (4i+h),(4i+2+h), phys ^n5
      const int p1 = ((4 * i + h) ^ n5) * 16;
      const int p2 = ((4 * i + 2 + h) ^ n5) * 16;
      int4 c0 = *(const int4*)(bt + p1);
      int4 c1 = *(const int4*)(bt + p2);
      intx8 cw = {c0.x, c0.y, c0.z, c0.w, c1.x, c1.y, c1.z, c1.w};
      ya = __builtin_amdgcn_mfma_scale_f32_32x32x64_f8f6f4(
          ar[i], cw, ya, 0, 0, 0, 0x7F7F7F7F, 0, 0x7F7F7F7F);
      yb = __builtin_amdgcn_mfma_scale_f32_32x32x64_f8f6f4(
          br[i], cw, yb, 0, 0, 0, 0x7F7F7F7F, 0, 0x7F7F7F7F);
    }
    __builtin_amdgcn_s_setprio(0);

    // epilogue: mask diag (aa/bb eye AND ab/ba label -- label re-added
    // exactly in finalize), exp-sum at fixed max 10.
    const int ct = csplit * 16 + u;       // global 32-col tile index in view
    const bool dtile = ((ct >> 2) == rb);
    const int colg = ct * 32 + n5;
#pragma unroll
    for (int r = 0; r < 16; ++r) {
      float va = ya[r], vb = yb[r];
      if (dtile) {
        const int rowg = r0 + w * 32 + (r & 3) + 8 * (r >> 2) + 4 * h;
        if (rowg == colg) { va = NEG_BIG; vb = NEG_BIG; }
      }
      mx[r] = fmaxf(mx[r], va);
      la[r] += exp2f(fmaf(va, SCL2, -C2));
      lb[r] += exp2f(fmaf(vb, SCL2, -C2));
    }
  }

  // emit partial sums / max for this split
#pragma unroll
  for (int off = 1; off < 32; off <<= 1)
#pragma unroll
    for (int r = 0; r < 16; ++r) {
      la[r] += __shfl_xor(la[r], off);
      lb[r] += __shfl_xor(lb[r], off);
      mx[r] = fmaxf(mx[r], __shfl_xor(mx[r], off));
    }
  if (n5 == 0) {
#pragma unroll
    for (int r = 0; r < 16; ++r) {
      const int row = r0 + w * 32 + (r & 3) + 8 * (r >> 2) + 4 * h;
      pSA[split * BN + row] = la[r];
      pMA[split * BN + row] = mx[r] * SCL;  // logit-domain max
      pSB[split * BN + row] = lb[r];
    }
  }
}

// ---------------- finalize: merge 16 splits, add label, reduce ------------
__global__ void __launch_bounds__(256) finalize_kernel(
    const float* __restrict__ pSA, const float* __restrict__ pMA,
    const float* __restrict__ pSB, const float* __restrict__ diag,
    float* __restrict__ out) {
  const int row = blockIdx.x * 256 + threadIdx.x;
  float SA = 0.f, SB = 0.f, MA = NEG_BIG;
#pragma unroll
  for (int s = 0; s < NSPLIT; ++s) {
    SA += pSA[s * BN + row];
    SB += pSB[s * BN + row];
    MA = fmaxf(MA, pMA[s * BN + row]);
  }
  const float d = diag[row];
  const float eL = exp2f(fmaf(d, 1.44269504f, -C2));  // exp(d-10)
  float lseA = 10.0f + logf(SA + eL);
  float lseB = 10.0f + logf(SB + eL);
  float lossi = (lseA - d) + (lseB - d);
  float corr = (d >= MA) ? 1.f : 0.f;  // argmax(full_a)==label
#pragma unroll
  for (int off = 32; off > 0; off >>= 1) {
    lossi += __shfl_xor(lossi, off);
    corr += __shfl_xor(corr, off);
  }
  __shared__ float sred[2][4];
  if ((threadIdx.x & 63) == 0) {
    int w = threadIdx.x >> 6;
    sred[0][w] = lossi; sred[1][w] = corr;
  }
  __syncthreads();
  if (threadIdx.x == 0) {
    float ls = sred[0][0] + sred[0][1] + sred[0][2] + sred[0][3];
    float cs = sred[1][0] + sred[1][1] + sred[1][2] + sred[1][3];
    atomicAdd(&out[0], ls * (1.0f / 8192.0f));    // mean over rows, /2
    atomicAdd(&out[1], cs * (100.0f / 4096.0f));  // accuracy %
  }
}

extern "C" void kernel_launch(void* const* d_in, const int* in_sizes, int n_in,
                              void* d_out, int out_size, void* d_ws, size_t ws_size,
                              hipStream_t stream) {
  const float* A = (const float*)d_in[0];
  const float* Bv = (const float*)d_in[1];
  unsigned char* An = (unsigned char*)d_ws;                   // 4096x512 fp8
  unsigned char* Bn = An + (size_t)BN * DK;                   // 4096x512 fp8
  float* diag = (float*)(Bn + (size_t)BN * DK);               // 4096 f32
  float* pSA = diag + BN;                                     // [16][4096] f32
  float* pMA = pSA + NSPLIT * BN;                             // [16][4096] f32
  float* pSB = pMA + NSPLIT * BN;                             // [16][4096] f32
  float* out = (float*)d_out;

  prep_kernel<<<BN / 4, 256, 0, stream>>>(A, Bv, An, Bn, diag, out);
  tiles_kernel<<<dim3(32, 16), 256, 0, stream>>>(An, Bn, pSA, pMA, pSB);
  finalize_kernel<<<BN / 256, 256, 0, stream>>>(pSA, pMA, pSB, diag, out);
}

// Round 2
// 184.545 us; speedup vs baseline: 1.1397x; 1.1397x over previous
//
#include <hip/hip_runtime.h>
#include <stdint.h>

// SimCLR loss, B=4096, D=512, TAU=0.1.  out[0]=loss, out[1]=acc(%).
//
// Round 12: two-pass skeleton (single frag set, ~145 live VGPRs, no spill --
// round-11's merged a/b frags spilled ~100 regs/thread = 435MB scratch
// traffic) + the round-11 machinery that verified correct:
//  - 5-bit XOR swizzle (phys chunk p of col c holds logical p^c): zero LDS
//    bank conflicts (R11-measured, vs R10's 4.19M 4-way).
//  - 32-col tiles (16KB) x 4 LDS buffers, 3-deep prefetch, counted
//    s_waitcnt vmcnt(8) + raw s_barrier per iter (T3/T4). Pipeline drains
//    once at the pass boundary, then re-primes (keeps vmcnt accounting
//    clean across the mid-kernel frag reload).
//  - s_setprio(1) around the MFMA cluster (T5).
// Pass A (a-row frags): full_a exp-sums + max. Pass B (b-row frags): full_b
// exp-sums. Tiles restaged per pass (L2-hot, 4MB dataset).

#define BN 4096
#define DK 512            // K elements = bytes per row in fp8
#define NSPLIT 16
#define NT 16             // 32-col tiles per split
#define NEG_BIG -1e30f
#define SCL 0.15625f      // 1/(8*8*TAU)
#define SCL2 0.225396744f // SCL * log2(e)
#define C2 14.4269504f    // 10 * log2(e)
#define TILE_BYTES (32 * DK)  // 16 KB per 32-col fp8 tile

typedef __attribute__((ext_vector_type(16))) float floatx16;
typedef __attribute__((ext_vector_type(8))) int intx8;

// ---------------- prep: normalize, fp8-pack (K-permuted), label, zero -----
// Permuted layout: byte position kc2*32 + h*16 + t*8 + j holds original
// k = kc2*32 + t*16 + h*8 + j.  16B chunk (kc2,h) = K=16-sub-block operand
// bytes; two consecutive chunks (2i,h),(2i+1,h) = one K=64 MX operand half.
__global__ void __launch_bounds__(256) prep_kernel(
    const float* __restrict__ A, const float* __restrict__ Bv,
    unsigned char* __restrict__ An, unsigned char* __restrict__ Bn,
    float* __restrict__ diag, float* __restrict__ out) {
  if (blockIdx.x == 0 && threadIdx.x < 2) out[threadIdx.x] = 0.0f;
  const int w = threadIdx.x >> 6, lane = threadIdx.x & 63;
  const int row = blockIdx.x * 4 + w;
  const float4* pa4 = (const float4*)(A + (size_t)row * DK);
  const float4* pb4 = (const float4*)(Bv + (size_t)row * DK);
  float4 a0 = pa4[lane * 2], a1 = pa4[lane * 2 + 1];  // k = lane*8 .. +7
  float4 b0 = pb4[lane * 2], b1 = pb4[lane * 2 + 1];
  float ssa = a0.x * a0.x + a0.y * a0.y + a0.z * a0.z + a0.w * a0.w +
              a1.x * a1.x + a1.y * a1.y + a1.z * a1.z + a1.w * a1.w;
  float ssb = b0.x * b0.x + b0.y * b0.y + b0.z * b0.z + b0.w * b0.w +
              b1.x * b1.x + b1.y * b1.y + b1.z * b1.z + b1.w * b1.w;
  float sab = a0.x * b0.x + a0.y * b0.y + a0.z * b0.z + a0.w * b0.w +
              a1.x * b1.x + a1.y * b1.y + a1.z * b1.z + a1.w * b1.w;
#pragma unroll
  for (int off = 32; off > 0; off >>= 1) {
    ssa += __shfl_xor(ssa, off);
    ssb += __shfl_xor(ssb, off);
    sab += __shfl_xor(sab, off);
  }
  float na = fmaxf(sqrtf(ssa), 1e-12f);
  float nb = fmaxf(sqrtf(ssb), 1e-12f);
  const float s = 8.0f;  // fp8 pre-scale: keeps elems mid-range in e4m3
  float sa = s / na, sb = s / nb;
  const int doff = (lane >> 2) * 32 + (lane & 1) * 16 + ((lane >> 1) & 1) * 8;
  {
    int v0 = __builtin_amdgcn_cvt_pk_fp8_f32(a0.x * sa, a0.y * sa, 0, false);
    v0 = __builtin_amdgcn_cvt_pk_fp8_f32(a0.z * sa, a0.w * sa, v0, true);
    int v1 = __builtin_amdgcn_cvt_pk_fp8_f32(a1.x * sa, a1.y * sa, 0, false);
    v1 = __builtin_amdgcn_cvt_pk_fp8_f32(a1.z * sa, a1.w * sa, v1, true);
    int2 pv; pv.x = v0; pv.y = v1;
    *(int2*)(An + (size_t)row * DK + doff) = pv;
  }
  {
    int v0 = __builtin_amdgcn_cvt_pk_fp8_f32(b0.x * sb, b0.y * sb, 0, false);
    v0 = __builtin_amdgcn_cvt_pk_fp8_f32(b0.z * sb, b0.w * sb, v0, true);
    int v1 = __builtin_amdgcn_cvt_pk_fp8_f32(b1.x * sb, b1.y * sb, 0, false);
    v1 = __builtin_amdgcn_cvt_pk_fp8_f32(b1.z * sb, b1.w * sb, v1, true);
    int2 pv; pv.x = v0; pv.y = v1;
    *(int2*)(Bn + (size_t)row * DK + doff) = pv;
  }
  if (lane == 0) diag[row] = (sab / (na * nb)) * 10.0f;  // exact fp32 /TAU
}

// ---------------- tiles: MX fp8 MFMA, two passes, pipelined staging -------
// grid = (32 row-blocks, 16 col-splits) = 512 blocks = 2/CU. 4 waves/block,
// wave owns 32 rows. Split covers 512 cols of ONE view (0-7: An, 8-15: Bn).
// Pass 0: a-row frags -> full_a sums+max. Pass 1: b-row frags -> full_b.
__global__ void __launch_bounds__(256, 2) tiles_kernel(
    const unsigned char* __restrict__ An, const unsigned char* __restrict__ Bn,
    float* __restrict__ pSA, float* __restrict__ pMA, float* __restrict__ pSB) {
  __shared__ __align__(16) unsigned char smem[4 * TILE_BYTES];  // 64 KB

  const int rb = blockIdx.x;     // 0..31 (128-row panel)
  const int split = blockIdx.y;  // 0..15
  const int tid = threadIdx.x;
  const int lane = tid & 63, w = tid >> 6;
  const int n5 = lane & 31, h = lane >> 5;
  const int r0 = rb * 128;
  const int myrow = r0 + w * 32 + n5;
  const int csplit = split & 7;
  const unsigned char* __restrict__ csrc = (split < 8) ? An : Bn;

  // K=64 MX row operands (ONE view at a time): aw[i] = chunks (2i,h)||(2i+1,h)
  intx8 aw[8];
  auto loadfrags = [&](const unsigned char* base) {
    const unsigned char* p = base + (size_t)myrow * DK + h * 16;
#pragma unroll
    for (int i = 0; i < 8; ++i) {
      int4 c0 = *(const int4*)(p + i * 64);
      int4 c1 = *(const int4*)(p + i * 64 + 32);
      intx8 v = {c0.x, c0.y, c0.z, c0.w, c1.x, c1.y, c1.z, c1.w};
      aw[i] = v;
    }
  };

  // stage one 32-col tile (16 KB): wave w stages colpairs w*4..w*4+3.
  // DMA dest linear (base + laneid*16); 5-bit XOR swizzle via pre-swizzled
  // global source: physical chunk p of col cl holds logical chunk p^cl.
  auto stage = [&](int bu, int t) {
    unsigned char* buf = smem + bu * TILE_BYTES;
    const int cb = csplit * 512 + t * 32;
#pragma unroll
    for (int ii = 0; ii < 4; ++ii) {
      const int cp = w * 4 + ii;
      const int cl = cp * 2 + h;
      const unsigned char* src =
          csrc + (size_t)(cb + cl) * DK + ((n5 ^ cl) * 16);
      __builtin_amdgcn_global_load_lds(
          (const __attribute__((address_space(1))) void*)src,
          (__attribute__((address_space(3))) void*)(buf + cp * 1024),
          16, 0, 0);
    }
  };

  float l[16], mx[16];
  const unsigned char* bb = smem + (size_t)n5 * DK;

#pragma unroll
  for (int pass = 0; pass < 2; ++pass) {
    loadfrags(pass ? Bn : An);
#pragma unroll
    for (int r = 0; r < 16; ++r) {
      l[r] = 0.f;
      if (pass == 0) mx[r] = NEG_BIG;
    }
    // prime the pipeline 3 deep (older in-flight ops -- frag loads, prior
    // stores -- are strictly older in vmcnt order, so counted waits below
    // remain correct: the 8 newest ops are always the 2 youngest tiles)
    stage(0, 0);
    stage(1, 1);
    stage(2, 2);

#pragma unroll
    for (int u = 0; u < NT; ++u) {
      // tile u complete once <=8 newer ops (tiles u+1,u+2) remain
      if (u < NT - 2)       asm volatile("s_waitcnt vmcnt(8)" ::: "memory");
      else if (u == NT - 2) asm volatile("s_waitcnt vmcnt(4)" ::: "memory");
      else                  asm volatile("s_waitcnt vmcnt(0)" ::: "memory");
      __builtin_amdgcn_s_barrier();
      __builtin_amdgcn_sched_barrier(0);
      // all waves have finished reading tile u-1 (consumed before the
      // previous barrier), so buffer (u+3)&3 may be overwritten now
      if (u + 3 < NT) stage((u + 3) & 3, u + 3);

      floatx16 ya;
#pragma unroll
      for (int r = 0; r < 16; ++r) ya[r] = 0.f;

      const unsigned char* bt = bb + (u & 3) * TILE_BYTES;
      __builtin_amdgcn_s_setprio(1);
#pragma unroll
      for (int i = 0; i < 8; ++i) {
        // col n5's K=64 operand: logical chunks (4i+h),(4i+2+h), phys ^n5
        const int p1 = ((4 * i + h) ^ n5) * 16;
        const int p2 = ((4 * i + 2 + h) ^ n5) * 16;
        int4 c0 = *(const int4*)(bt + p1);
        int4 c1 = *(const int4*)(bt + p2);
        intx8 cw = {c0.x, c0.y, c0.z, c0.w, c1.x, c1.y, c1.z, c1.w};
        ya = __builtin_amdgcn_mfma_scale_f32_32x32x64_f8f6f4(
            aw[i], cw, ya, 0, 0, 0, 0x7F7F7F7F, 0, 0x7F7F7F7F);
      }
      __builtin_amdgcn_s_setprio(0);

      // epilogue: mask diag (aa/bb eye AND ab/ba label -- label re-added
      // exactly in finalize), exp-sum at fixed max 10.
      const int ct = csplit * 16 + u;      // global 32-col tile idx in view
      const bool dtile = ((ct >> 2) == rb);
      const int colg = ct * 32 + n5;
#pragma unroll
      for (int r = 0; r < 16; ++r) {
        float v = ya[r];
        if (dtile) {
          const int rowg = r0 + w * 32 + (r & 3) + 8 * (r >> 2) + 4 * h;
          if (rowg == colg) v = NEG_BIG;
        }
        if (pass == 0) mx[r] = fmaxf(mx[r], v);
        l[r] += exp2f(fmaf(v, SCL2, -C2));
      }
    }

    // emit this pass's partial sums (+max for pass A)
#pragma unroll
    for (int off = 1; off < 32; off <<= 1)
#pragma unroll
      for (int r = 0; r < 16; ++r) {
        l[r] += __shfl_xor(l[r], off);
        if (pass == 0) mx[r] = fmaxf(mx[r], __shfl_xor(mx[r], off));
      }
    if (n5 == 0) {
#pragma unroll
      for (int r = 0; r < 16; ++r) {
        const int row = r0 + w * 32 + (r & 3) + 8 * (r >> 2) + 4 * h;
        if (pass == 0) {
          pSA[split * BN + row] = l[r];
          pMA[split * BN + row] = mx[r] * SCL;  // logit-domain max
        } else {
          pSB[split * BN + row] = l[r];
        }
      }
    }
  }
}

// ---------------- finalize: merge 16 splits, add label, reduce ------------
__global__ void __launch_bounds__(256) finalize_kernel(
    const float* __restrict__ pSA, const float* __restrict__ pMA,
    const float* __restrict__ pSB, const float* __restrict__ diag,
    float* __restrict__ out) {
  const int row = blockIdx.x * 256 + threadIdx.x;
  float SA = 0.f, SB = 0.f, MA = NEG_BIG;
#pragma unroll
  for (int s = 0; s < NSPLIT; ++s) {
    SA += pSA[s * BN + row];
    SB += pSB[s * BN + row];
    MA = fmaxf(MA, pMA[s * BN + row]);
  }
  const float d = diag[row];
  const float eL = exp2f(fmaf(d, 1.44269504f, -C2));  // exp(d-10)
  float lseA = 10.0f + logf(SA + eL);
  float lseB = 10.0f + logf(SB + eL);
  float lossi = (lseA - d) + (lseB - d);
  float corr = (d >= MA) ? 1.f : 0.f;  // argmax(full_a)==label
#pragma unroll
  for (int off = 32; off > 0; off >>= 1) {
    lossi += __shfl_xor(lossi, off);
    corr += __shfl_xor(corr, off);
  }
  __shared__ float sred[2][4];
  if ((threadIdx.x & 63) == 0) {
    int w = threadIdx.x >> 6;
    sred[0][w] = lossi; sred[1][w] = corr;
  }
  __syncthreads();
  if (threadIdx.x == 0) {
    float ls = sred[0][0] + sred[0][1] + sred[0][2] + sred[0][3];
    float cs = sred[1][0] + sred[1][1] + sred[1][2] + sred[1][3];
    atomicAdd(&out[0], ls * (1.0f / 8192.0f));    // mean over rows, /2
    atomicAdd(&out[1], cs * (100.0f / 4096.0f));  // accuracy %
  }
}

extern "C" void kernel_launch(void* const* d_in, const int* in_sizes, int n_in,
                              void* d_out, int out_size, void* d_ws, size_t ws_size,
                              hipStream_t stream) {
  const float* A = (const float*)d_in[0];
  const float* Bv = (const float*)d_in[1];
  unsigned char* An = (unsigned char*)d_ws;                   // 4096x512 fp8
  unsigned char* Bn = An + (size_t)BN * DK;                   // 4096x512 fp8
  float* diag = (float*)(Bn + (size_t)BN * DK);               // 4096 f32
  float* pSA = diag + BN;                                     // [16][4096] f32
  float* pMA = pSA + NSPLIT * BN;                             // [16][4096] f32
  float* pSB = pMA + NSPLIT * BN;                             // [16][4096] f32
  float* out = (float*)d_out;

  prep_kernel<<<BN / 4, 256, 0, stream>>>(A, Bv, An, Bn, diag, out);
  tiles_kernel<<<dim3(32, 16), 256, 0, stream>>>(An, Bn, pSA, pMA, pSB);
  finalize_kernel<<<BN / 256, 256, 0, stream>>>(pSA, pMA, pSB, diag, out);
}

// Round 3
// 134.072 us; speedup vs baseline: 1.5688x; 1.3765x over previous
//
#include <hip/hip_runtime.h>
#include <stdint.h>

// SimCLR loss, B=4096, D=512, TAU=0.1.  out[0]=loss, out[1]=acc(%).
//
// Round 13: Round-12 structure with the u/pass loops forced to RUNTIME
// (#pragma unroll 1).  R12's full 32x unroll let the scheduler hoist
// ds_reads across iteration bodies -> >128 live VGPRs -> ~100 regs spilled
// -> 270MB scratch traffic = the whole 154us (R12 counters: WRITE_SIZE
// 152MB, MfmaUtil 0.08%).  R10's runtime loop compiled at 116 VGPR, no
// spill.  Everything else retained from R12 (verified correct there):
//  - 5-bit XOR swizzle (phys chunk p of col c holds logical p^c): zero LDS
//    bank conflicts (R11/R12-measured; R10's 3-bit swizzle had 4.19M).
//  - 32-col tiles (16KB) x 4 LDS buffers, 3-deep prefetch, counted
//    s_waitcnt vmcnt(8) + raw s_barrier per iter (T3/T4); drains once at
//    the pass boundary then re-primes.
//  - s_setprio(1) around the MFMA cluster (T5).
// Pass A (a-row frags): full_a exp-sums + max. Pass B (b-row frags): full_b
// exp-sums. Tiles restaged per pass (L2-hot, 4MB dataset).

#define BN 4096
#define DK 512            // K elements = bytes per row in fp8
#define NSPLIT 16
#define NT 16             // 32-col tiles per split
#define NEG_BIG -1e30f
#define SCL 0.15625f      // 1/(8*8*TAU)
#define SCL2 0.225396744f // SCL * log2(e)
#define C2 14.4269504f    // 10 * log2(e)
#define TILE_BYTES (32 * DK)  // 16 KB per 32-col fp8 tile

typedef __attribute__((ext_vector_type(16))) float floatx16;
typedef __attribute__((ext_vector_type(8))) int intx8;

// ---------------- prep: normalize, fp8-pack (K-permuted), label, zero -----
// Permuted layout: byte position kc2*32 + h*16 + t*8 + j holds original
// k = kc2*32 + t*16 + h*8 + j.  16B chunk (kc2,h) = K=16-sub-block operand
// bytes; two consecutive chunks (2i,h),(2i+1,h) = one K=64 MX operand half.
__global__ void __launch_bounds__(256) prep_kernel(
    const float* __restrict__ A, const float* __restrict__ Bv,
    unsigned char* __restrict__ An, unsigned char* __restrict__ Bn,
    float* __restrict__ diag, float* __restrict__ out) {
  if (blockIdx.x == 0 && threadIdx.x < 2) out[threadIdx.x] = 0.0f;
  const int w = threadIdx.x >> 6, lane = threadIdx.x & 63;
  const int row = blockIdx.x * 4 + w;
  const float4* pa4 = (const float4*)(A + (size_t)row * DK);
  const float4* pb4 = (const float4*)(Bv + (size_t)row * DK);
  float4 a0 = pa4[lane * 2], a1 = pa4[lane * 2 + 1];  // k = lane*8 .. +7
  float4 b0 = pb4[lane * 2], b1 = pb4[lane * 2 + 1];
  float ssa = a0.x * a0.x + a0.y * a0.y + a0.z * a0.z + a0.w * a0.w +
              a1.x * a1.x + a1.y * a1.y + a1.z * a1.z + a1.w * a1.w;
  float ssb = b0.x * b0.x + b0.y * b0.y + b0.z * b0.z + b0.w * b0.w +
              b1.x * b1.x + b1.y * b1.y + b1.z * b1.z + b1.w * b1.w;
  float sab = a0.x * b0.x + a0.y * b0.y + a0.z * b0.z + a0.w * b0.w +
              a1.x * b1.x + a1.y * b1.y + a1.z * b1.z + a1.w * b1.w;
#pragma unroll
  for (int off = 32; off > 0; off >>= 1) {
    ssa += __shfl_xor(ssa, off);
    ssb += __shfl_xor(ssb, off);
    sab += __shfl_xor(sab, off);
  }
  float na = fmaxf(sqrtf(ssa), 1e-12f);
  float nb = fmaxf(sqrtf(ssb), 1e-12f);
  const float s = 8.0f;  // fp8 pre-scale: keeps elems mid-range in e4m3
  float sa = s / na, sb = s / nb;
  const int doff = (lane >> 2) * 32 + (lane & 1) * 16 + ((lane >> 1) & 1) * 8;
  {
    int v0 = __builtin_amdgcn_cvt_pk_fp8_f32(a0.x * sa, a0.y * sa, 0, false);
    v0 = __builtin_amdgcn_cvt_pk_fp8_f32(a0.z * sa, a0.w * sa, v0, true);
    int v1 = __builtin_amdgcn_cvt_pk_fp8_f32(a1.x * sa, a1.y * sa, 0, false);
    v1 = __builtin_amdgcn_cvt_pk_fp8_f32(a1.z * sa, a1.w * sa, v1, true);
    int2 pv; pv.x = v0; pv.y = v1;
    *(int2*)(An + (size_t)row * DK + doff) = pv;
  }
  {
    int v0 = __builtin_amdgcn_cvt_pk_fp8_f32(b0.x * sb, b0.y * sb, 0, false);
    v0 = __builtin_amdgcn_cvt_pk_fp8_f32(b0.z * sb, b0.w * sb, v0, true);
    int v1 = __builtin_amdgcn_cvt_pk_fp8_f32(b1.x * sb, b1.y * sb, 0, false);
    v1 = __builtin_amdgcn_cvt_pk_fp8_f32(b1.z * sb, b1.w * sb, v1, true);
    int2 pv; pv.x = v0; pv.y = v1;
    *(int2*)(Bn + (size_t)row * DK + doff) = pv;
  }
  if (lane == 0) diag[row] = (sab / (na * nb)) * 10.0f;  // exact fp32 /TAU
}

// ---------------- tiles: MX fp8 MFMA, two passes, pipelined staging -------
// grid = (32 row-blocks, 16 col-splits) = 512 blocks = 2/CU. 4 waves/block,
// wave owns 32 rows. Split covers 512 cols of ONE view (0-7: An, 8-15: Bn).
// Pass 0: a-row frags -> full_a sums+max. Pass 1: b-row frags -> full_b.
__global__ void __launch_bounds__(256, 2) tiles_kernel(
    const unsigned char* __restrict__ An, const unsigned char* __restrict__ Bn,
    float* __restrict__ pSA, float* __restrict__ pMA, float* __restrict__ pSB) {
  __shared__ __align__(16) unsigned char smem[4 * TILE_BYTES];  // 64 KB

  const int rb = blockIdx.x;     // 0..31 (128-row panel)
  const int split = blockIdx.y;  // 0..15
  const int tid = threadIdx.x;
  const int lane = tid & 63, w = tid >> 6;
  const int n5 = lane & 31, h = lane >> 5;
  const int r0 = rb * 128;
  const int myrow = r0 + w * 32 + n5;
  const int csplit = split & 7;
  const unsigned char* __restrict__ csrc = (split < 8) ? An : Bn;

  // K=64 MX row operands (ONE view at a time): aw[i] = chunks (2i,h)||(2i+1,h)
  intx8 aw[8];
  auto loadfrags = [&](const unsigned char* base) {
    const unsigned char* p = base + (size_t)myrow * DK + h * 16;
#pragma unroll
    for (int i = 0; i < 8; ++i) {
      int4 c0 = *(const int4*)(p + i * 64);
      int4 c1 = *(const int4*)(p + i * 64 + 32);
      intx8 v = {c0.x, c0.y, c0.z, c0.w, c1.x, c1.y, c1.z, c1.w};
      aw[i] = v;
    }
  };

  // stage one 32-col tile (16 KB): wave w stages colpairs w*4..w*4+3.
  // DMA dest linear (base + laneid*16); 5-bit XOR swizzle via pre-swizzled
  // global source: physical chunk p of col cl holds logical chunk p^cl.
  auto stage = [&](int bu, int t) {
    unsigned char* buf = smem + bu * TILE_BYTES;
    const int cb = csplit * 512 + t * 32;
#pragma unroll
    for (int ii = 0; ii < 4; ++ii) {
      const int cp = w * 4 + ii;
      const int cl = cp * 2 + h;
      const unsigned char* src =
          csrc + (size_t)(cb + cl) * DK + ((n5 ^ cl) * 16);
      __builtin_amdgcn_global_load_lds(
          (const __attribute__((address_space(1))) void*)src,
          (__attribute__((address_space(3))) void*)(buf + cp * 1024),
          16, 0, 0);
    }
  };

  float l[16], mx[16];
  const unsigned char* bb = smem + (size_t)n5 * DK;

#pragma unroll 1
  for (int pass = 0; pass < 2; ++pass) {
    loadfrags(pass ? Bn : An);
#pragma unroll
    for (int r = 0; r < 16; ++r) {
      l[r] = 0.f;
      if (pass == 0) mx[r] = NEG_BIG;
    }
    // prime the pipeline 3 deep (older in-flight ops -- frag loads, prior
    // stores -- are strictly older in vmcnt order, so counted waits below
    // remain correct: the 8 newest ops are always the 2 youngest tiles)
    stage(0, 0);
    stage(1, 1);
    stage(2, 2);

#pragma unroll 1
    for (int u = 0; u < NT; ++u) {
      // tile u complete once <=8 newer ops (tiles u+1,u+2) remain
      if (u < NT - 2)       asm volatile("s_waitcnt vmcnt(8)" ::: "memory");
      else if (u == NT - 2) asm volatile("s_waitcnt vmcnt(4)" ::: "memory");
      else                  asm volatile("s_waitcnt vmcnt(0)" ::: "memory");
      __builtin_amdgcn_s_barrier();
      __builtin_amdgcn_sched_barrier(0);
      // all waves have finished reading tile u-1 (consumed before the
      // previous barrier), so buffer (u+3)&3 may be overwritten now
      if (u + 3 < NT) stage((u + 3) & 3, u + 3);

      floatx16 ya;
#pragma unroll
      for (int r = 0; r < 16; ++r) ya[r] = 0.f;

      const unsigned char* bt = bb + (u & 3) * TILE_BYTES;
      __builtin_amdgcn_s_setprio(1);
#pragma unroll
      for (int i = 0; i < 8; ++i) {
        // col n5's K=64 operand: logical chunks (4i+h),(4i+2+h), phys ^n5
        const int p1 = ((4 * i + h) ^ n5) * 16;
        const int p2 = ((4 * i + 2 + h) ^ n5) * 16;
        int4 c0 = *(const int4*)(bt + p1);
        int4 c1 = *(const int4*)(bt + p2);
        intx8 cw = {c0.x, c0.y, c0.z, c0.w, c1.x, c1.y, c1.z, c1.w};
        ya = __builtin_amdgcn_mfma_scale_f32_32x32x64_f8f6f4(
            aw[i], cw, ya, 0, 0, 0, 0x7F7F7F7F, 0, 0x7F7F7F7F);
      }
      __builtin_amdgcn_s_setprio(0);

      // epilogue: mask diag (aa/bb eye AND ab/ba label -- label re-added
      // exactly in finalize), exp-sum at fixed max 10.
      const int ct = csplit * 16 + u;      // global 32-col tile idx in view
      const bool dtile = ((ct >> 2) == rb);
      const int colg = ct * 32 + n5;
#pragma unroll
      for (int r = 0; r < 16; ++r) {
        float v = ya[r];
        if (dtile) {
          const int rowg = r0 + w * 32 + (r & 3) + 8 * (r >> 2) + 4 * h;
          if (rowg == colg) v = NEG_BIG;
        }
        if (pass == 0) mx[r] = fmaxf(mx[r], v);
        l[r] += exp2f(fmaf(v, SCL2, -C2));
      }
    }

    // emit this pass's partial sums (+max for pass A)
#pragma unroll
    for (int off = 1; off < 32; off <<= 1)
#pragma unroll
      for (int r = 0; r < 16; ++r) {
        l[r] += __shfl_xor(l[r], off);
        if (pass == 0) mx[r] = fmaxf(mx[r], __shfl_xor(mx[r], off));
      }
    if (n5 == 0) {
#pragma unroll
      for (int r = 0; r < 16; ++r) {
        const int row = r0 + w * 32 + (r & 3) + 8 * (r >> 2) + 4 * h;
        if (pass == 0) {
          pSA[split * BN + row] = l[r];
          pMA[split * BN + row] = mx[r] * SCL;  // logit-domain max
        } else {
          pSB[split * BN + row] = l[r];
        }
      }
    }
  }
}

// ---------------- finalize: merge 16 splits, add label, reduce ------------
__global__ void __launch_bounds__(256) finalize_kernel(
    const float* __restrict__ pSA, const float* __restrict__ pMA,
    const float* __restrict__ pSB, const float* __restrict__ diag,
    float* __restrict__ out) {
  const int row = blockIdx.x * 256 + threadIdx.x;
  float SA = 0.f, SB = 0.f, MA = NEG_BIG;
#pragma unroll
  for (int s = 0; s < NSPLIT; ++s) {
    SA += pSA[s * BN + row];
    SB += pSB[s * BN + row];
    MA = fmaxf(MA, pMA[s * BN + row]);
  }
  const float d = diag[row];
  const float eL = exp2f(fmaf(d, 1.44269504f, -C2));  // exp(d-10)
  float lseA = 10.0f + logf(SA + eL);
  float lseB = 10.0f + logf(SB + eL);
  float lossi = (lseA - d) + (lseB - d);
  float corr = (d >= MA) ? 1.f : 0.f;  // argmax(full_a)==label
#pragma unroll
  for (int off = 32; off > 0; off >>= 1) {
    lossi += __shfl_xor(lossi, off);
    corr += __shfl_xor(corr, off);
  }
  __shared__ float sred[2][4];
  if ((threadIdx.x & 63) == 0) {
    int w = threadIdx.x >> 6;
    sred[0][w] = lossi; sred[1][w] = corr;
  }
  __syncthreads();
  if (threadIdx.x == 0) {
    float ls = sred[0][0] + sred[0][1] + sred[0][2] + sred[0][3];
    float cs = sred[1][0] + sred[1][1] + sred[1][2] + sred[1][3];
    atomicAdd(&out[0], ls * (1.0f / 8192.0f));    // mean over rows, /2
    atomicAdd(&out[1], cs * (100.0f / 4096.0f));  // accuracy %
  }
}

extern "C" void kernel_launch(void* const* d_in, const int* in_sizes, int n_in,
                              void* d_out, int out_size, void* d_ws, size_t ws_size,
                              hipStream_t stream) {
  const float* A = (const float*)d_in[0];
  const float* Bv = (const float*)d_in[1];
  unsigned char* An = (unsigned char*)d_ws;                   // 4096x512 fp8
  unsigned char* Bn = An + (size_t)BN * DK;                   // 4096x512 fp8
  float* diag = (float*)(Bn + (size_t)BN * DK);               // 4096 f32
  float* pSA = diag + BN;                                     // [16][4096] f32
  float* pMA = pSA + NSPLIT * BN;                             // [16][4096] f32
  float* pSB = pMA + NSPLIT * BN;                             // [16][4096] f32
  float* out = (float*)d_out;

  prep_kernel<<<BN / 4, 256, 0, stream>>>(A, Bv, An, Bn, diag, out);
  tiles_kernel<<<dim3(32, 16), 256, 0, stream>>>(An, Bn, pSA, pMA, pSB);
  finalize_kernel<<<BN / 256, 256, 0, stream>>>(pSA, pMA, pSB, diag, out);
}